// Round 1
// 180.241 us; speedup vs baseline: 1.8279x; 1.8279x over previous
//
#include <hip/hip_runtime.h>
#include <hip/hip_bf16.h>

// EulerIntegrator: B=4096, D=1024, R=256, steps=8, dt=0.01
// Persistent per-row-tile kernel: each block owns 16 rows, runs all steps.
// R2 change: 1024-thread blocks (16 waves/CU vs 8) to double latency hiding;
// per-wave work halved (GEMM1: 1 nt-tile/wave, GEMM2: 4 nt-tiles/wave).
// Output epilogue staged through LDS (aliases v_lds) for full-line float4 writes.
// GEMM1: P[16x256] = v[16x1024] @ U   (bf16 MFMA 16x16x32)
// GEMM2: G[16x1024] = (P*P)[16x256] @ W
// v kept fp32 in registers (C/D-layout ownership), bf16 mirror in LDS for MFMA A.

#define BB 4096
#define DD 1024
#define RR 256
#define DT 0.01f

typedef __attribute__((ext_vector_type(8))) short short8;   // 8 bf16 = 4 VGPRs
typedef __attribute__((ext_vector_type(4))) float floatx4;  // MFMA acc

static __device__ inline unsigned short f2bf(float f) {
    union { float f; unsigned int u; } c; c.f = f;
    unsigned int u = c.u;
    u += 0x7fffu + ((u >> 16) & 1u);   // round-to-nearest-even
    return (unsigned short)(u >> 16);
}

// Pack U [1024][256] and W [256][1024] (fp32 row-major) into bf16 MFMA
// B-fragment order: dst[(kt*NT + nt)*64 + lane] = 8 bf16, element j =
// M[kt*32 + (lane>>4)*8 + j][nt*16 + (lane&15)].
__global__ void pack_kernel(const float* __restrict__ U, const float* __restrict__ W,
                            short* __restrict__ Up, short* __restrict__ Wp) {
    int t = blockIdx.x * blockDim.x + threadIdx.x;  // 0..65535
    if (t < 32768) {
        // U: ktiles=32, ntiles=16
        int lane = t & 63;
        int nl = lane & 15, kq = lane >> 4;
        int idx = t >> 6;            // kt*16 + nt
        int nt = idx & 15, kt = idx >> 4;
        short8 o;
#pragma unroll
        for (int j = 0; j < 8; j++) {
            int k = kt * 32 + kq * 8 + j;
            int n = nt * 16 + nl;
            o[j] = (short)f2bf(U[k * RR + n]);
        }
        ((short8*)Up)[t] = o;
    } else {
        // W: ktiles=8, ntiles=64
        int t2 = t - 32768;
        int lane = t2 & 63;
        int nl = lane & 15, kq = lane >> 4;
        int idx = t2 >> 6;           // kt*64 + nt
        int nt = idx & 63, kt = idx >> 6;
        short8 o;
#pragma unroll
        for (int j = 0; j < 8; j++) {
            int k = kt * 32 + kq * 8 + j;
            int n = nt * 16 + nl;
            o[j] = (short)f2bf(W[k * DD + n]);
        }
        ((short8*)Wp)[t2] = o;
    }
}

__global__ __launch_bounds__(1024, 4)
void euler_kernel(const float* __restrict__ x0,
                  const float* __restrict__ v0,
                  const float* __restrict__ force,
                  const short8* __restrict__ Up,
                  const short8* __restrict__ Wp,
                  const int* __restrict__ steps_p,
                  float* __restrict__ out) {
    // LDS: bf16 v tile (padded stride 1032 -> b128 A-reads at bank floor),
    // bf16 p^2 tile (stride 264). v_lds is re-aliased as the f32 output stage.
    __shared__ __align__(16) short v_lds[16][1032];   // 33.0 KB
    __shared__ __align__(16) short p2_lds[16][264];   //  8.4 KB

    const int tid  = threadIdx.x;
    const int wave = tid >> 6;          // 0..15
    const int lane = tid & 63;
    const int nl   = lane & 15;         // M (A) / N (B) / col (C)
    const int quad = lane >> 4;         // 0..3
    const int row0 = blockIdx.x * 16;

    const int steps = steps_p[0];

    // Ownership (matches MFMA C/D layout of GEMM2, 4 tiles/wave):
    // element (t, r): row = 4*quad + r, col = 64*wave + 16*t + nl
    float v_reg[4][4], f_reg[4][4], sv[4][4];

#pragma unroll
    for (int t = 0; t < 4; t++) {
        int col = 64 * wave + 16 * t + nl;
#pragma unroll
        for (int r = 0; r < 4; r++) {
            int row = 4 * quad + r;
            long g = (long)(row0 + row) * DD + col;
            v_reg[t][r] = v0[g];
            f_reg[t][r] = force[g];
            sv[t][r] = 0.0f;
            v_lds[row][col] = (short)f2bf(v_reg[t][r]);
        }
    }
    __syncthreads();

    for (int s = 0; s < steps; s++) {
        // ---------------- GEMM1: P = v @ U ; wave computes nt = wave
        floatx4 acc1 = {0.f, 0.f, 0.f, 0.f};
#pragma unroll 4
        for (int kt = 0; kt < 32; kt++) {
            short8 a = *(const short8*)&v_lds[nl][kt * 32 + quad * 8];
            short8 b = Up[(kt * 16 + wave) * 64 + lane];
            acc1 = __builtin_amdgcn_mfma_f32_16x16x32_bf16(a, b, acc1, 0, 0, 0);
        }
        // epilogue: p^2 -> LDS (D layout: row = 4*quad + r, col = 16*wave + nl)
#pragma unroll
        for (int r = 0; r < 4; r++) {
            float p = acc1[r];
            p2_lds[4 * quad + r][16 * wave + nl] = (short)f2bf(p * p);
        }
        __syncthreads();

        // ---------------- GEMM2: G = p2 @ W ; wave computes nt = 4w..4w+3
        floatx4 acc[4];
#pragma unroll
        for (int t = 0; t < 4; t++) acc[t] = (floatx4){0.f, 0.f, 0.f, 0.f};
#pragma unroll 2
        for (int kt = 0; kt < 8; kt++) {
            short8 a = *(const short8*)&p2_lds[nl][kt * 32 + quad * 8];
#pragma unroll
            for (int t = 0; t < 4; t++) {
                short8 b = Wp[(kt * 64 + 4 * wave + t) * 64 + lane];
                acc[t] = __builtin_amdgcn_mfma_f32_16x16x32_bf16(a, b, acc[t], 0, 0, 0);
            }
        }
        // epilogue: Euler update, refresh bf16 v in LDS
#pragma unroll
        for (int t = 0; t < 4; t++) {
            int col = 64 * wave + 16 * t + nl;
#pragma unroll
            for (int r = 0; r < 4; r++) {
                int row = 4 * quad + r;
                float gma = acc[t][r];
                sv[t][r] += v_reg[t][r];                       // x accumulates pre-update v
                v_reg[t][r] += DT * (f_reg[t][r] - gma);
                v_lds[row][col] = (short)f2bf(v_reg[t][r]);
            }
        }
        __syncthreads();
    }

    // ---------------- outputs: [cx | cv], cx = x0 + dt * sum(v_t)
    // Stage 8 rows at a time as f32 in the (now dead) v_lds, then write
    // fully-coalesced float4 lines (fixes 64B-fragment partial-line writes),
    // and read x0 linearly as float4.
    float (*stage)[1032] = reinterpret_cast<float(*)[1032]>(&v_lds[0][0]);
    const float4* x4 = reinterpret_cast<const float4*>(x0);
    float4* out4 = reinterpret_cast<float4*>(out);

    for (int sel = 0; sel < 2; sel++) {          // 0: cx, 1: cv
        for (int half = 0; half < 2; half++) {   // rows 0..7, 8..15
            __syncthreads();
            if ((quad >> 1) == half) {
#pragma unroll
                for (int t = 0; t < 4; t++) {
                    int col = 64 * wave + 16 * t + nl;
#pragma unroll
                    for (int r = 0; r < 4; r++) {
                        int lrow = (4 * quad + r) & 7;
                        stage[lrow][col] = sel ? v_reg[t][r] : DT * sv[t][r];
                    }
                }
            }
            __syncthreads();
            // linear copy: 8 rows x 1024 cols = 2048 float4, 2 per thread
            for (int i = tid; i < 2048; i += 1024) {
                int lrow = i >> 8;               // 256 float4 per row
                int c4 = i & 255;
                long gi = (long)(row0 + half * 8 + lrow) * 256 + c4;
                float4 val = *(const float4*)&stage[lrow][c4 * 4];
                if (sel == 0) {
                    float4 xv = x4[gi];
                    val.x += xv.x; val.y += xv.y; val.z += xv.z; val.w += xv.w;
                    out4[gi] = val;
                } else {
                    out4[(long)BB * 256 + gi] = val;
                }
            }
        }
    }
}

extern "C" void kernel_launch(void* const* d_in, const int* in_sizes, int n_in,
                              void* d_out, int out_size, void* d_ws, size_t ws_size,
                              hipStream_t stream) {
    const float* x     = (const float*)d_in[0];
    const float* v     = (const float*)d_in[1];
    const float* force = (const float*)d_in[2];
    const float* U     = (const float*)d_in[3];
    const float* W     = (const float*)d_in[4];
    const int*   steps = (const int*)d_in[5];

    short* Up = (short*)d_ws;                 // 32768 * 16B = 512 KB
    short* Wp = Up + 32768 * 8;               // 512 KB

    pack_kernel<<<256, 256, 0, stream>>>(U, W, Up, Wp);
    euler_kernel<<<256, 1024, 0, stream>>>(x, v, force,
                                           (const short8*)Up, (const short8*)Wp,
                                           steps, (float*)d_out);
}